// Round 1
// baseline (1089.511 us; speedup 1.0000x reference)
//
#include <hip/hip_runtime.h>
#include <math.h>

#define NLEV 12
#define TSIZE (1u << 19)
#define TMASK (TSIZE - 1u)
#define DOUT 257
#define PPB 256            // points per block == threads per block
#define EMB 24             // L*F feature dim
#define RSTRIDE 28         // emb row stride in floats: 112 B, 16B-aligned for b128 reads

struct ResArr { float r[NLEV]; };

__global__ __launch_bounds__(256)
void hashgrid_head_kernel(const float* __restrict__ xin,
                          const float* __restrict__ tables,
                          const float* __restrict__ Wm,
                          const float* __restrict__ bias,
                          float* __restrict__ out,
                          int N, ResArr res)
{
    __shared__ float emb[PPB * RSTRIDE];   // 28672 B
    const int tid  = threadIdx.x;
    const int base = blockIdx.x * PPB;
    const int p    = base + tid;

    // ---- W column for j = tid (coalesced: lane t reads W[k*257 + t]) ----
    float wcol[EMB];
#pragma unroll
    for (int k = 0; k < EMB; ++k) wcol[k] = Wm[k * DOUT + tid];
    const float bj = bias[tid];

    // wave 0 additionally owns column 256 (broadcast load, redundant compute)
    const bool extra = (tid < 64);
    float wext[EMB];
    float bext = 0.0f;
    if (extra) {
#pragma unroll
        for (int k = 0; k < EMB; ++k) wext[k] = Wm[k * DOUT + 256];
        bext = bias[256];
    }

    // ---- Phase A: hash-grid encode one point per thread ----
    if (p < N) {
        const float px = xin[3 * p + 0];
        const float py = xin[3 * p + 1];
        const float pz = xin[3 * p + 2];
#pragma unroll 2
        for (int l = 0; l < NLEV; ++l) {
            const float rf = res.r[l];
            const float sx = px * rf, sy = py * rf, sz = pz * rf;
            const float gx = floorf(sx), gy = floorf(sy), gz = floorf(sz);
            const float tx = sx - gx, ty = sy - gy, tz = sz - gz;
            const unsigned ix = (unsigned)gx, iy = (unsigned)gy, iz = (unsigned)gz;
            // primes: {1, 2654435761, 805459861} for dims (x,y,z); uint32 wraparound
            const unsigned hx0 = ix,                  hx1 = ix + 1u;
            const unsigned hy0 = iy * 2654435761u,    hy1 = hy0 + 2654435761u;
            const unsigned hz0 = iz * 805459861u,     hz1 = hz0 + 805459861u;
            const float2* __restrict__ tab = (const float2*)tables + (size_t)l * TSIZE;
            // corner i: bits (x,y,z) = ((i>>2)&1, (i>>1)&1, i&1)
            float2 f0 = tab[(hx0 ^ hy0 ^ hz0) & TMASK];
            float2 f1 = tab[(hx0 ^ hy0 ^ hz1) & TMASK];
            float2 f2 = tab[(hx0 ^ hy1 ^ hz0) & TMASK];
            float2 f3 = tab[(hx0 ^ hy1 ^ hz1) & TMASK];
            float2 f4 = tab[(hx1 ^ hy0 ^ hz0) & TMASK];
            float2 f5 = tab[(hx1 ^ hy0 ^ hz1) & TMASK];
            float2 f6 = tab[(hx1 ^ hy1 ^ hz0) & TMASK];
            float2 f7 = tab[(hx1 ^ hy1 ^ hz1) & TMASK];
            const float u0 = 1.0f - tx, u1 = tx;
            const float v0 = 1.0f - ty, v1 = ty;
            const float s0 = 1.0f - tz, s1 = tz;
            const float w0 = (u0 * v0) * s0;
            const float w1 = (u0 * v0) * s1;
            const float w2 = (u0 * v1) * s0;
            const float w3 = (u0 * v1) * s1;
            const float w4 = (u1 * v0) * s0;
            const float w5 = (u1 * v0) * s1;
            const float w6 = (u1 * v1) * s0;
            const float w7 = (u1 * v1) * s1;
            float a = w0 * f0.x;
            float b = w0 * f0.y;
            a = fmaf(w1, f1.x, a);  b = fmaf(w1, f1.y, b);
            a = fmaf(w2, f2.x, a);  b = fmaf(w2, f2.y, b);
            a = fmaf(w3, f3.x, a);  b = fmaf(w3, f3.y, b);
            a = fmaf(w4, f4.x, a);  b = fmaf(w4, f4.y, b);
            a = fmaf(w5, f5.x, a);  b = fmaf(w5, f5.y, b);
            a = fmaf(w6, f6.x, a);  b = fmaf(w6, f6.y, b);
            a = fmaf(w7, f7.x, a);  b = fmaf(w7, f7.y, b);
            *(float2*)&emb[tid * RSTRIDE + 2 * l] = make_float2(a, b);
        }
    }

    __syncthreads();

    // ---- Phase B: head GEMV, thread owns column j=tid across all tile points ----
    const int nvalid = min(PPB, N - base);
    for (int n = 0; n < nvalid; ++n) {
        const float4* e4 = (const float4*)&emb[n * RSTRIDE];  // 16B-aligned, broadcast reads
        float4 q0 = e4[0], q1 = e4[1], q2 = e4[2], q3 = e4[3], q4 = e4[4], q5 = e4[5];
        float e[EMB] = {q0.x, q0.y, q0.z, q0.w, q1.x, q1.y, q1.z, q1.w,
                        q2.x, q2.y, q2.z, q2.w, q3.x, q3.y, q3.z, q3.w,
                        q4.x, q4.y, q4.z, q4.w, q5.x, q5.y, q5.z, q5.w};
        float acc = bj;
#pragma unroll
        for (int k = 0; k < EMB; ++k) acc = fmaf(e[k], wcol[k], acc);
        out[(size_t)(base + n) * DOUT + tid] = acc;
        if (extra) {
            float acc2 = bext;
#pragma unroll
            for (int k = 0; k < EMB; ++k) acc2 = fmaf(e[k], wext[k], acc2);
            if (tid == 0) out[(size_t)(base + n) * DOUT + 256] = acc2;
        }
    }
}

extern "C" void kernel_launch(void* const* d_in, const int* in_sizes, int n_in,
                              void* d_out, int out_size, void* d_ws, size_t ws_size,
                              hipStream_t stream) {
    const float* xin    = (const float*)d_in[0];
    const float* tables = (const float*)d_in[1];
    const float* Wm     = (const float*)d_in[2];
    const float* bias   = (const float*)d_in[3];
    float* out = (float*)d_out;
    const int N = in_sizes[0] / 3;

    // Replicate numpy: RES = floor(BASE_RES * growth**arange(L)), growth = exp((ln 2048 - ln 16)/11).
    // Same glibc exp/log/pow chain as numpy on this host -> bit-identical RES.
    ResArr res;
    const double growth = exp((log(2048.0) - log(16.0)) / 11.0);
    for (int l = 0; l < NLEV; ++l)
        res.r[l] = (float)floor(16.0 * pow(growth, (double)l));

    const int grid = (N + PPB - 1) / PPB;
    hipLaunchKernelGGL(hashgrid_head_kernel, dim3(grid), dim3(PPB), 0, stream,
                       xin, tables, Wm, bias, out, N, res);
}